// Round 11
// baseline (329.419 us; speedup 1.0000x reference)
//
#include <hip/hip_runtime.h>
#include <hip/hip_bf16.h>

#define NN 50000
#define NE 800000
#define HD 128
#define BN_EPS 1e-5f
#define MSTR 132     // padded LDS stride (floats)
#define NBUK 782     // ceil(NN/64) coarse buckets
#define PB 200       // partition blocks for bucket count/scatter
#define CHUNK 4000   // NE / PB

typedef __attribute__((ext_vector_type(8))) __bf16 bf16x8;
typedef __attribute__((ext_vector_type(4))) __bf16 bf16x4;
typedef __attribute__((ext_vector_type(4))) float floatx4;

// ---------------- merged prep: W split/pack + x cast + bucket count ----------------
// blocks [0,320): wprep; [320,3445): cast; [3445,3645): bcount.
// gbtot zeroed via hipMemsetAsync before this kernel (cross-block ordering!).
__global__ __launch_bounds__(256) void k_prep(const float* __restrict__ W0,
                                              const float* __restrict__ W1,
                                              const float* __restrict__ W2,
                                              const float* __restrict__ W3,
                                              const float* __restrict__ W4,
                                              __bf16* __restrict__ Bh,
                                              __bf16* __restrict__ Bl,
                                              const float* __restrict__ X,
                                              __bf16* __restrict__ Y,
                                              const int* __restrict__ dst,
                                              int* __restrict__ gbtot) {
    __shared__ int h[NBUK];
    const int b = blockIdx.x;
    if (b < 320) {
        // ---- W prep: split bf16 hi/lo, packed in wave-load order ----
        const int t = b * 256 + threadIdx.x;          // 81920 = 5*128*128
        const int m = t >> 14;
        const int rem = t & 16383;
        const int n = rem >> 7;
        const int k = rem & 127;
        const float* W = (m == 0) ? W0 : (m == 1) ? W1 : (m == 2) ? W2 : (m == 3) ? W3 : W4;
        const float w = W[k * HD + n];
        const __bf16 hi = (__bf16)w;
        const int ct = n >> 4, lm = n & 15;
        const int ks = k >> 5, lq = (k & 31) >> 3, j = k & 7;
        const int lane = lq * 16 + lm;
        const size_t o = (size_t)m * HD * HD + (size_t)(((ct * 4 + ks) * 64) + lane) * 8 + j;
        Bh[o] = hi;
        Bl[o] = (__bf16)(w - (float)hi);
    } else if (b < 320 + 3125) {
        // ---- f32 -> bf16 cast, 8 elems/lane ----
        const int i8 = ((b - 320) * 256 + threadIdx.x) * 8;
        const float4 a = *(const float4*)&X[i8];
        const float4 c = *(const float4*)&X[i8 + 4];
        bf16x8 o;
        o[0] = (__bf16)a.x; o[1] = (__bf16)a.y; o[2] = (__bf16)a.z; o[3] = (__bf16)a.w;
        o[4] = (__bf16)c.x; o[5] = (__bf16)c.y; o[6] = (__bf16)c.z; o[7] = (__bf16)c.w;
        *(bf16x8*)&Y[i8] = o;
    } else {
        // ---- bucket count (LDS histogram) ----
        for (int i = threadIdx.x; i < NBUK; i += 256) h[i] = 0;
        __syncthreads();
        const int e0 = (b - (320 + 3125)) * CHUNK;
        for (int i = threadIdx.x; i < CHUNK; i += 256)
            atomicAdd(&h[dst[e0 + i] >> 6], 1);
        __syncthreads();
        for (int i = threadIdx.x; i < NBUK; i += 256) {
            const int v = h[i];
            if (v) atomicAdd(&gbtot[i], v);
        }
    }
}

// ---------------- CSR build: scan / scatter / finalize ----------------
__global__ __launch_bounds__(256) void k_bscan(const int* __restrict__ gbtot,
                                               int* __restrict__ bbase,
                                               int* __restrict__ gcur,
                                               int* __restrict__ rowptr) {
    __shared__ int sh[256];
    const int t = threadIdx.x;
    int v[4];
    int s = 0;
#pragma unroll
    for (int j = 0; j < 4; ++j) {
        const int idx = t * 4 + j;
        v[j] = (idx < NBUK) ? gbtot[idx] : 0;
        s += v[j];
    }
    sh[t] = s;
    __syncthreads();
#pragma unroll
    for (int st = 1; st < 256; st <<= 1) {
        int add = (t >= st) ? sh[t - st] : 0;
        __syncthreads();
        sh[t] += add;
        __syncthreads();
    }
    int run = sh[t] - s;  // exclusive
#pragma unroll
    for (int j = 0; j < 4; ++j) {
        const int idx = t * 4 + j;
        if (idx < NBUK) { bbase[idx] = run; gcur[idx] = run; }
        run += v[j];
    }
    if (t == 255) bbase[NBUK] = run;   // == NE
    if (t == 0) rowptr[NN] = NE;
}

__global__ __launch_bounds__(256) void k_bscatter(const int* __restrict__ src,
                                                  const int* __restrict__ dst,
                                                  int* __restrict__ gcur,
                                                  int2* __restrict__ pairs) {
    __shared__ int h[NBUK];
    __shared__ int cur[NBUK];
    for (int i = threadIdx.x; i < NBUK; i += 256) h[i] = 0;
    __syncthreads();
    const int e0 = blockIdx.x * CHUNK;
    for (int i = threadIdx.x; i < CHUNK; i += 256)
        atomicAdd(&h[dst[e0 + i] >> 6], 1);
    __syncthreads();
    for (int i = threadIdx.x; i < NBUK; i += 256) {
        const int v = h[i];
        if (v) cur[i] = atomicAdd(&gcur[i], v);   // block-reserve per bucket
    }
    __syncthreads();
    for (int i = threadIdx.x; i < CHUNK; i += 256) {
        const int d = dst[e0 + i];
        const int pos = atomicAdd(&cur[d >> 6], 1);
        pairs[pos] = make_int2(src[e0 + i], d);
    }
}

__global__ __launch_bounds__(256) void k_csrfin(const int2* __restrict__ pairs,
                                                const int* __restrict__ bbase,
                                                int* __restrict__ rowptr,
                                                int* __restrict__ esrc) {
    __shared__ int cnt[64], lof[64], cur[64];
    const int b = blockIdx.x;
    const int s = bbase[b], e = bbase[b + 1];
    const int tid = threadIdx.x;
    if (tid < 64) cnt[tid] = 0;
    __syncthreads();
    for (int i = s + tid; i < e; i += 256)
        atomicAdd(&cnt[pairs[i].y & 63], 1);
    __syncthreads();
    if (tid == 0) {
        int r = 0;
#pragma unroll
        for (int j = 0; j < 64; ++j) { lof[j] = r; cur[j] = r; r += cnt[j]; }
    }
    __syncthreads();
    if (tid < 64) {
        const int node = b * 64 + tid;
        if (node < NN) rowptr[node] = s + lof[tid];
    }
    for (int i = s + tid; i < e; i += 256) {
        const int2 p = pairs[i];
        const int pos = atomicAdd(&cur[p.y & 63], 1);
        esrc[s + pos] = p.x;
    }
}

// ---------------- helper: split float8 into bf16 hi/lo fragments ----------------
__device__ __forceinline__ void split8(const float4 a, const float4 b,
                                       bf16x8& hi, bf16x8& lo) {
    hi[0] = (__bf16)a.x; lo[0] = (__bf16)(a.x - (float)hi[0]);
    hi[1] = (__bf16)a.y; lo[1] = (__bf16)(a.y - (float)hi[1]);
    hi[2] = (__bf16)a.z; lo[2] = (__bf16)(a.z - (float)hi[2]);
    hi[3] = (__bf16)a.w; lo[3] = (__bf16)(a.w - (float)hi[3]);
    hi[4] = (__bf16)b.x; lo[4] = (__bf16)(b.x - (float)hi[4]);
    hi[5] = (__bf16)b.y; lo[5] = (__bf16)(b.y - (float)hi[5]);
    hi[6] = (__bf16)b.z; lo[6] = (__bf16)(b.z - (float)hi[6]);
    hi[7] = (__bf16)b.w; lo[7] = (__bf16)(b.w - (float)hi[7]);
}

// ---------------- helper: unpack-accumulate 8 bf16 into two float4 ----------------
__device__ __forceinline__ void addb8(float4& a, float4& b, const bf16x8 v) {
    a.x += (float)v[0]; a.y += (float)v[1]; a.z += (float)v[2]; a.w += (float)v[3];
    b.x += (float)v[4]; b.y += (float)v[5]; b.z += (float)v[6]; b.w += (float)v[7];
}

// ---------------- gather-aggregate, column-phase split, XCD-pinned ----------------
// 4 phases x 32 cols (= one 64B line per edge per phase). phase = (blockIdx&7)>>1
// pins each phase to one XCD pair (blockIdx%8->XCD heuristic): per-XCD working set
// = 3.2 MB Z-slice, fits the 4 MB per-XCD L2 -> gather served at L2 rate.
// 128 thr: 32 nodes/block, 4 lanes/node. Perf-only heuristic; correct regardless.
__global__ __launch_bounds__(128) void k_aggb(const __bf16* __restrict__ Z,
                                              const int* __restrict__ rowptr,
                                              const int* __restrict__ esrc,
                                              float* __restrict__ H) {
    const int i = blockIdx.x;
    const int xcd = i & 7;
    const int phase = xcd >> 1;
    const int nb = ((i >> 3) << 1) | (xcd & 1);   // node-block 0..1563
    const int g = threadIdx.x >> 2;               // node sub-index 0..31
    const int lg = threadIdx.x & 3;
    const int node = nb * 32 + g;
    if (node >= NN) return;
    const int cb = phase * 32 + lg * 8;           // 8 cols (16 B) per lane
    const int start = rowptr[node], end = rowptr[node + 1];
    float4 a = {0.f, 0.f, 0.f, 0.f}, b = {0.f, 0.f, 0.f, 0.f};
    addb8(a, b, *(const bf16x8*)&Z[(size_t)node * HD + cb]);
    int k = start;
    for (; k + 8 <= end; k += 8) {
        const int s0 = esrc[k + 0], s1 = esrc[k + 1];
        const int s2 = esrc[k + 2], s3 = esrc[k + 3];
        const int s4 = esrc[k + 4], s5 = esrc[k + 5];
        const int s6 = esrc[k + 6], s7 = esrc[k + 7];
        const bf16x8 v0 = *(const bf16x8*)&Z[(size_t)s0 * HD + cb];
        const bf16x8 v1 = *(const bf16x8*)&Z[(size_t)s1 * HD + cb];
        const bf16x8 v2 = *(const bf16x8*)&Z[(size_t)s2 * HD + cb];
        const bf16x8 v3 = *(const bf16x8*)&Z[(size_t)s3 * HD + cb];
        const bf16x8 v4 = *(const bf16x8*)&Z[(size_t)s4 * HD + cb];
        const bf16x8 v5 = *(const bf16x8*)&Z[(size_t)s5 * HD + cb];
        const bf16x8 v6 = *(const bf16x8*)&Z[(size_t)s6 * HD + cb];
        const bf16x8 v7 = *(const bf16x8*)&Z[(size_t)s7 * HD + cb];
        addb8(a, b, v0); addb8(a, b, v1); addb8(a, b, v2); addb8(a, b, v3);
        addb8(a, b, v4); addb8(a, b, v5); addb8(a, b, v6); addb8(a, b, v7);
    }
    for (; k + 4 <= end; k += 4) {
        const int s0 = esrc[k + 0], s1 = esrc[k + 1];
        const int s2 = esrc[k + 2], s3 = esrc[k + 3];
        const bf16x8 v0 = *(const bf16x8*)&Z[(size_t)s0 * HD + cb];
        const bf16x8 v1 = *(const bf16x8*)&Z[(size_t)s1 * HD + cb];
        const bf16x8 v2 = *(const bf16x8*)&Z[(size_t)s2 * HD + cb];
        const bf16x8 v3 = *(const bf16x8*)&Z[(size_t)s3 * HD + cb];
        addb8(a, b, v0); addb8(a, b, v1); addb8(a, b, v2); addb8(a, b, v3);
    }
    for (; k < end; ++k) {
        const int s = esrc[k];
        addb8(a, b, *(const bf16x8*)&Z[(size_t)s * HD + cb]);
    }
    *(float4*)&H[(size_t)node * HD + cb] = a;
    *(float4*)&H[(size_t)node * HD + cb + 4] = b;
}

// ---------------- B staging (global -> regs -> LDS), 16 chunks of 1KB per ks-panel ----------------
// wave wid stages chunks [wid*4, wid*4+4): chunks 0-7 = hi ct0-7, 8-15 = lo ct0-7.
struct StageRegs { bf16x8 v[4]; };

__device__ __forceinline__ void stage_load(StageRegs& s, const __bf16* __restrict__ Bh,
                                           const __bf16* __restrict__ Bl,
                                           int ks, int wid, int lane) {
#pragma unroll
    for (int i = 0; i < 4; ++i) {
        const int chunk = wid * 4 + i;
        const int ct = chunk & 7;
        const __bf16* base = (chunk < 8) ? Bh : Bl;
        s.v[i] = *(const bf16x8*)&base[(size_t)(((ct * 4 + ks) * 64) + lane) * 8];
    }
}
__device__ __forceinline__ void stage_write(const StageRegs& s, __bf16* Bb,
                                            int wid, int lane) {
#pragma unroll
    for (int i = 0; i < 4; ++i) {
        const int chunk = wid * 4 + i;
        *(bf16x8*)&Bb[chunk * 512 + lane * 8] = s.v[i];
    }
}

// ---------------- helper: bf16x3 K-pass reading B panel from LDS (batched) ----------------
__device__ __forceinline__ void mfma_pass_lds(floatx4 (&acc)[8], const bf16x8 ah,
                                              const bf16x8 al, const __bf16* Bb,
                                              int lane) {
    bf16x8 bh[8], bl[8];
#pragma unroll
    for (int ct = 0; ct < 8; ++ct) {
        bh[ct] = *(const bf16x8*)&Bb[ct * 512 + lane * 8];
        bl[ct] = *(const bf16x8*)&Bb[(8 + ct) * 512 + lane * 8];
    }
    __builtin_amdgcn_sched_barrier(0);
#pragma unroll
    for (int ct = 0; ct < 8; ++ct) {
        acc[ct] = __builtin_amdgcn_mfma_f32_16x16x32_bf16(al, bh[ct], acc[ct], 0, 0, 0);
        acc[ct] = __builtin_amdgcn_mfma_f32_16x16x32_bf16(ah, bl[ct], acc[ct], 0, 0, 0);
        acc[ct] = __builtin_amdgcn_mfma_f32_16x16x32_bf16(ah, bh[ct], acc[ct], 0, 0, 0);
    }
}

// ---------------- fused GIN MLP: C = relu(relu(A@W1+b1)@W2+b2) ----------------
// B panels LDS-staged once per block, shared by all 4 waves. 8 phases (4 ks x 2
// GEMMs), double-buffered, T14 pattern: issue loads -> compute -> write -> barrier.
template <int STATS, int OUT16>
__global__ __launch_bounds__(256) void k_mlp(const float* __restrict__ A,
                                             const __bf16* __restrict__ Bh1,
                                             const __bf16* __restrict__ Bl1,
                                             const float* __restrict__ b1,
                                             const __bf16* __restrict__ Bh2,
                                             const __bf16* __restrict__ Bl2,
                                             const float* __restrict__ b2,
                                             float* __restrict__ C,
                                             __bf16* __restrict__ C16,
                                             float* __restrict__ pstat) {
    __shared__ float mid[4][16 * MSTR];   // 33792 B, per-wave scratch
    __shared__ __bf16 Bb[2][16 * 512];    // 32768 B, double-buffered B panel
    __shared__ float ssum[128], ssq[128];
    const int tid = threadIdx.x;
    const int wid = tid >> 6, lane = tid & 63;
    const int lq = lane >> 4, lm = lane & 15;
    if (STATS && tid < 128) { ssum[tid] = 0.f; ssq[tid] = 0.f; }
    const int rowbase = blockIdx.x * 64 + wid * 16;
    const int r0 = min(rowbase + lm, NN - 1);
    float* m = &mid[wid][0];

    // ---- A preload for GEMM1 (all 4 ks) ----
    bf16x8 ahv[4], alv[4];
    {
        float4 av[8];
#pragma unroll
        for (int ks = 0; ks < 4; ++ks) {
            const int kk = ks * 32 + lq * 8;
            av[ks * 2 + 0] = *(const float4*)&A[(size_t)r0 * HD + kk];
            av[ks * 2 + 1] = *(const float4*)&A[(size_t)r0 * HD + kk + 4];
        }
#pragma unroll
        for (int ks = 0; ks < 4; ++ks)
            split8(av[ks * 2], av[ks * 2 + 1], ahv[ks], alv[ks]);
    }
    // ---- prologue: stage phase-0 panel ----
    {
        StageRegs s;
        stage_load(s, Bh1, Bl1, 0, wid, lane);
        stage_write(s, &Bb[0][0], wid, lane);
    }
    __syncthreads();

    floatx4 acc[8];
#pragma unroll
    for (int j = 0; j < 8; ++j) acc[j] = (floatx4){0.f, 0.f, 0.f, 0.f};

#pragma unroll
    for (int p = 0; p < 8; ++p) {
        // 1. issue next-panel loads (hidden under compute)
        StageRegs s;
        if (p < 7) {
            const int pn = p + 1;
            stage_load(s, (pn < 4) ? Bh1 : Bh2, (pn < 4) ? Bl1 : Bl2, pn & 3, wid, lane);
        }
        // 2. compute this phase
        bf16x8 ah, al;
        if (p < 4) { ah = ahv[p]; al = alv[p]; }
        else {
            const int kk = (p & 3) * 32 + lq * 8;
            const float4 aa = *(const float4*)&m[lm * MSTR + kk];
            const float4 ab = *(const float4*)&m[lm * MSTR + kk + 4];
            split8(aa, ab, ah, al);
        }
        mfma_pass_lds(acc, ah, al, &Bb[p & 1][0], lane);
        // 3. GEMM1 epilogue between phases 3 and 4 (per-wave mid, no barrier needed)
        if (p == 3) {
#pragma unroll
            for (int ct = 0; ct < 8; ++ct) {
                const int col = ct * 16 + lm;
                const float bcol = b1[col];
#pragma unroll
                for (int r = 0; r < 4; ++r)
                    m[(lq * 4 + r) * MSTR + col] = fmaxf(acc[ct][r] + bcol, 0.f);
            }
#pragma unroll
            for (int j = 0; j < 8; ++j) acc[j] = (floatx4){0.f, 0.f, 0.f, 0.f};
        }
        // 4. land the staged panel, fence all waves
        if (p < 7) stage_write(s, &Bb[(p + 1) & 1][0], wid, lane);
        __syncthreads();
    }
    // ---- epilogue: transpose via LDS -> coalesced stores (+stats) ----
#pragma unroll
    for (int ct = 0; ct < 8; ++ct) {
        const int col = ct * 16 + lm;
        const float bcol = b2[col];
#pragma unroll
        for (int r = 0; r < 4; ++r)
            m[(lq * 4 + r) * MSTR + col] = fmaxf(acc[ct][r] + bcol, 0.f);
    }
    float s0 = 0.f, s1 = 0.f, s2 = 0.f, s3 = 0.f;
    float q0 = 0.f, q1 = 0.f, q2 = 0.f, q3 = 0.f;
    const int c0 = (lane * 4) & 127;
#pragma unroll
    for (int p = 0; p < 8; ++p) {
        const int idx = p * 256 + lane * 4;
        const int r = idx >> 7;
        const float4 v = *(const float4*)&m[r * MSTR + c0];
        const int row = rowbase + r;
        if (row < NN) {
            if (OUT16) {
                bf16x4 o;
                o[0] = (__bf16)v.x; o[1] = (__bf16)v.y;
                o[2] = (__bf16)v.z; o[3] = (__bf16)v.w;
                *(bf16x4*)&C16[(size_t)row * HD + c0] = o;
            } else {
                *(float4*)&C[(size_t)row * HD + c0] = v;
            }
            if (STATS) {
                s0 += v.x; q0 = fmaf(v.x, v.x, q0);
                s1 += v.y; q1 = fmaf(v.y, v.y, q1);
                s2 += v.z; q2 = fmaf(v.z, v.z, q2);
                s3 += v.w; q3 = fmaf(v.w, v.w, q3);
            }
        }
    }
    if (STATS) {
        s0 += __shfl_xor(s0, 32); q0 += __shfl_xor(q0, 32);
        s1 += __shfl_xor(s1, 32); q1 += __shfl_xor(q1, 32);
        s2 += __shfl_xor(s2, 32); q2 += __shfl_xor(q2, 32);
        s3 += __shfl_xor(s3, 32); q3 += __shfl_xor(q3, 32);
        if (lane < 32) {
            atomicAdd(&ssum[c0 + 0], s0); atomicAdd(&ssq[c0 + 0], q0);
            atomicAdd(&ssum[c0 + 1], s1); atomicAdd(&ssq[c0 + 1], q1);
            atomicAdd(&ssum[c0 + 2], s2); atomicAdd(&ssq[c0 + 2], q2);
            atomicAdd(&ssum[c0 + 3], s3); atomicAdd(&ssq[c0 + 3], q3);
        }
        __syncthreads();
        if (tid < 128) {   // contention-free partial store
            pstat[(size_t)blockIdx.x * 256 + tid] = ssum[tid];
            pstat[(size_t)blockIdx.x * 256 + 128 + tid] = ssq[tid];
        }
    }
}

// ---------------- projection GEMM: LDS-staged B, BN-on-A + z-write + p partial stats ----------------
__global__ __launch_bounds__(256) void k_proj(const float* __restrict__ Z2,
                                              const float* __restrict__ bnsc,
                                              const float* __restrict__ bnsh,
                                              float* __restrict__ Zout,
                                              const __bf16* __restrict__ Bh,
                                              const __bf16* __restrict__ Bl,
                                              const float* __restrict__ bias,
                                              float* __restrict__ C,
                                              float* __restrict__ pstat) {
    __shared__ union {                    // B panel (phases) then epilogue tile
        __bf16 bb[2][16 * 512];           // 32768 B
        float tb[4][16 * MSTR];           // 33792 B
    } u;
    __shared__ float ssum[128], ssq[128];
    const int tid = threadIdx.x;
    const int wid = tid >> 6, lane = tid & 63;
    const int lq = lane >> 4, lm = lane & 15;
    if (tid < 128) { ssum[tid] = 0.f; ssq[tid] = 0.f; }
    const int rowbase = blockIdx.x * 64 + wid * 16;
    const int r0 = min(rowbase + lm, NN - 1);
    const bool rowok = (rowbase + lm) < NN;
    float* m = &u.tb[wid][0];

    // ---- preload A' = BN(z2) for all ks; write Zout ----
    bf16x8 ahv[4], alv[4];
#pragma unroll
    for (int ks = 0; ks < 4; ++ks) {
        const int kk = ks * 32 + lq * 8;
        const float4 za = *(const float4*)&Z2[(size_t)r0 * HD + kk];
        const float4 zb = *(const float4*)&Z2[(size_t)r0 * HD + kk + 4];
        const float4 sca = *(const float4*)&bnsc[kk];
        const float4 scb = *(const float4*)&bnsc[kk + 4];
        const float4 sha = *(const float4*)&bnsh[kk];
        const float4 shb = *(const float4*)&bnsh[kk + 4];
        float4 aa, ab;
        aa.x = fmaf(za.x, sca.x, sha.x); aa.y = fmaf(za.y, sca.y, sha.y);
        aa.z = fmaf(za.z, sca.z, sha.z); aa.w = fmaf(za.w, sca.w, sha.w);
        ab.x = fmaf(zb.x, scb.x, shb.x); ab.y = fmaf(zb.y, scb.y, shb.y);
        ab.z = fmaf(zb.z, scb.z, shb.z); ab.w = fmaf(zb.w, scb.w, shb.w);
        if (rowok) {
            *(float4*)&Zout[(size_t)r0 * HD + kk] = aa;
            *(float4*)&Zout[(size_t)r0 * HD + kk + 4] = ab;
        }
        split8(aa, ab, ahv[ks], alv[ks]);
    }
    // ---- prologue: stage ks=0 panel ----
    {
        StageRegs s;
        stage_load(s, Bh, Bl, 0, wid, lane);
        stage_write(s, &u.bb[0][0], wid, lane);
    }
    __syncthreads();

    floatx4 acc[8];
#pragma unroll
    for (int j = 0; j < 8; ++j) acc[j] = (floatx4){0.f, 0.f, 0.f, 0.f};
#pragma unroll
    for (int p = 0; p < 4; ++p) {
        StageRegs s;
        if (p < 3) stage_load(s, Bh, Bl, p + 1, wid, lane);
        mfma_pass_lds(acc, ahv[p], alv[p], &u.bb[p & 1][0], lane);
        if (p < 3) stage_write(s, &u.bb[(p + 1) & 1][0], wid, lane);
        __syncthreads();
    }
    // ---- epilogue: transpose (tb overlays bb; barrier above fences last reads) ----
#pragma unroll
    for (int ct = 0; ct < 8; ++ct) {
        const int col = ct * 16 + lm;
        const float bcol = bias[col];
#pragma unroll
        for (int r = 0; r < 4; ++r)
            m[(lq * 4 + r) * MSTR + col] = acc[ct][r] + bcol;
    }
    float s0 = 0.f, s1 = 0.f, s2 = 0.f, s3 = 0.f;
    float q0 = 0.f, q1 = 0.f, q2 = 0.f, q3 = 0.f;
    const int c0 = (lane * 4) & 127;
#pragma unroll
    for (int p = 0; p < 8; ++p) {
        const int idx = p * 256 + lane * 4;
        const int r = idx >> 7;
        const float4 v = *(const float4*)&m[r * MSTR + c0];
        const int row = rowbase + r;
        if (row < NN) {
            *(float4*)&C[(size_t)row * HD + c0] = v;
            s0 += v.x; q0 = fmaf(v.x, v.x, q0);
            s1 += v.y; q1 = fmaf(v.y, v.y, q1);
            s2 += v.z; q2 = fmaf(v.z, v.z, q2);
            s3 += v.w; q3 = fmaf(v.w, v.w, q3);
        }
    }
    s0 += __shfl_xor(s0, 32); q0 += __shfl_xor(q0, 32);
    s1 += __shfl_xor(s1, 32); q1 += __shfl_xor(q1, 32);
    s2 += __shfl_xor(s2, 32); q2 += __shfl_xor(q2, 32);
    s3 += __shfl_xor(s3, 32); q3 += __shfl_xor(q3, 32);
    if (lane < 32) {
        atomicAdd(&ssum[c0 + 0], s0); atomicAdd(&ssq[c0 + 0], q0);
        atomicAdd(&ssum[c0 + 1], s1); atomicAdd(&ssq[c0 + 1], q1);
        atomicAdd(&ssum[c0 + 2], s2); atomicAdd(&ssq[c0 + 2], q2);
        atomicAdd(&ssum[c0 + 3], s3); atomicAdd(&ssq[c0 + 3], q3);
    }
    __syncthreads();
    if (tid < 128) {   // contention-free partial store
        pstat[(size_t)blockIdx.x * 256 + tid] = ssum[tid];
        pstat[(size_t)blockIdx.x * 256 + 128 + tid] = ssq[tid];
    }
}

// ---------------- stats reduce: NBLK x 256 partials -> 64 x 256 ----------------
__global__ __launch_bounds__(256) void k_sred(const float* __restrict__ ps, int nblk,
                                              float* __restrict__ out) {
    const int j = threadIdx.x;
    float acc = 0.f;
    for (int r = blockIdx.x; r < nblk; r += 64)
        acc += ps[(size_t)r * 256 + j];
    out[blockIdx.x * 256 + j] = acc;
}

// ---------------- BN finalize (sums 64 partial rows) ----------------
__global__ void k_bnfin(const float* __restrict__ pb2,
                        const float* __restrict__ gamma, const float* __restrict__ beta,
                        float* __restrict__ scale, float* __restrict__ shift) {
    const int c = threadIdx.x;
    float s = 0.f, q = 0.f;
    for (int b = 0; b < 64; ++b) {
        s += pb2[b * 256 + c];
        q += pb2[b * 256 + 128 + c];
    }
    const float mean = s * (1.f / NN);
    const float var = q * (1.f / NN) - mean * mean;
    const float sc = gamma[c] * rsqrtf(var + BN_EPS);
    scale[c] = sc;
    shift[c] = beta[c] - mean * sc;
}

// ---------------- BN apply + PReLU, float4, in-place ----------------
__global__ void k_bnapply(const float* __restrict__ X, const float* __restrict__ scale,
                          const float* __restrict__ shift, float* __restrict__ Y,
                          const float* __restrict__ pa) {
    const int i4 = (blockIdx.x * 256 + threadIdx.x) * 4;
    const int c = i4 & 127;
    const float4 sc = *(const float4*)&scale[c];
    const float4 sh = *(const float4*)&shift[c];
    const float4 v = *(const float4*)&X[i4];
    float4 y;
    y.x = fmaf(v.x, sc.x, sh.x);
    y.y = fmaf(v.y, sc.y, sh.y);
    y.z = fmaf(v.z, sc.z, sh.z);
    y.w = fmaf(v.w, sc.w, sh.w);
    const float a = pa[0];
    if (y.x < 0.f) y.x *= a;
    if (y.y < 0.f) y.y *= a;
    if (y.z < 0.f) y.z *= a;
    if (y.w < 0.f) y.w *= a;
    *(float4*)&Y[i4] = y;
}

extern "C" void kernel_launch(void* const* d_in, const int* in_sizes, int n_in,
                              void* d_out, int out_size, void* d_ws, size_t ws_size,
                              hipStream_t stream) {
    const float* x = (const float*)d_in[0];
    const int* ei = (const int*)d_in[1];
    const float* w0a = (const float*)d_in[2];
    const float* b0a = (const float*)d_in[3];
    const float* w0b = (const float*)d_in[4];
    const float* b0b = (const float*)d_in[5];
    const float* w1a = (const float*)d_in[6];
    const float* b1a = (const float*)d_in[7];
    const float* w1b = (const float*)d_in[8];
    const float* b1b = (const float*)d_in[9];
    const float* bng = (const float*)d_in[10];
    const float* bnb = (const float*)d_in[11];
    const float* pw  = (const float*)d_in[12];
    const float* pb  = (const float*)d_in[13];
    const float* pbng = (const float*)d_in[14];
    const float* pbnb = (const float*)d_in[15];
    const float* pa = (const float*)d_in[16];

    float* outZ = (float*)d_out;                    // (NN,128) f32 — z
    float* outP = outZ + (size_t)NN * HD;           // (NN,128) f32 — H scratch / z2 / p

    float* ws = (float*)d_ws;
    float* bufH = ws;                               // 25.6 MB: xb (bf16) + z1b/pairs
    float* st = bufH + (size_t)NN * HD;             // 1024 floats (scale/shift slots)
    int* rowptr = (int*)(st + 1024);                // NN+1 (+pad)
    int* esrc = rowptr + NN + 64;                   // NE
    int* gbtot = esrc + NE;                         // 782 (pad 800)
    int* bbase = gbtot + 800;                       // 783 (pad 800)
    int* gcur = bbase + 800;                        // 782 (pad 800)
    __bf16* wth = (__bf16*)(gcur + 800);            // 5*128*128 bf16 hi (packed)
    __bf16* wtl = wth + 5 * HD * HD;                // 5*128*128 bf16 lo (packed)
    float* ps1 = (float*)(wtl + 5 * HD * HD);       // 782*256 f32 — z-stat partials
    float* pb2a = ps1 + 800 * 256;                  // 64*256
    float* ps2 = pb2a + 64 * 256;                   // 782*256 — p-stat partials
    float* pb2b = ps2 + 800 * 256;                  // 64*256

    __bf16* xb  = (__bf16*)bufH;                    // (NN,128) bf16 — cast of x
    __bf16* z1b = xb + (size_t)NN * HD;             // (NN,128) bf16 — z1
    int2* pairs = (int2*)z1b;                       // 6.4 MB — CSR scratch (aliases z1b;
                                                    //   consumed by k_csrfin before z1b write)
    float* Hbuf = outP;                             // aggregate scratch (aliases outP)

    const int* srcv = ei;
    const int* dstv = ei + NE;

    const int ELV = (NN * HD) / (256 * 4);
    const int GB = (NN + 63) / 64;                  // 782
    const int AB = 782 * 8;                         // 6256: 4 phases x 1564 node-blocks (XCD-pinned)
    const int PREPB = 320 + 3125 + PB;              // 3645

    // ---- zero bucket totals, then merged prep (wprep ∥ cast ∥ bcount) ----
    hipMemsetAsync(gbtot, 0, 800 * sizeof(int), stream);
    k_prep<<<PREPB, 256, 0, stream>>>(w0a, w0b, w1a, w1b, pw, wth, wtl,
                                      x, xb, dstv, gbtot);

    // ---- CSR build: scan -> scatter pairs -> finalize ----
    k_bscan<<<1, 256, 0, stream>>>(gbtot, bbase, gcur, rowptr);
    k_bscatter<<<PB, 256, 0, stream>>>(srcv, dstv, gcur, pairs);
    k_csrfin<<<NBUK, 256, 0, stream>>>(pairs, bbase, rowptr, esrc);

    // ---- GIN layer 0: H = x + agg(x) (phase-split bf16 gather); z1b = relu(MLP0(H)) ----
    k_aggb<<<AB, 128, 0, stream>>>(xb, rowptr, esrc, Hbuf);
    k_mlp<0, 1><<<GB, 256, 0, stream>>>(Hbuf,
                                        wth + 0 * HD * HD, wtl + 0 * HD * HD, b0a,
                                        wth + 1 * HD * HD, wtl + 1 * HD * HD, b0b,
                                        nullptr, z1b, nullptr);

    // ---- GIN layer 1: H = z1 + agg(z1); z2 = relu(MLP1(H)) -> outP, partial z-stats ----
    k_aggb<<<AB, 128, 0, stream>>>(z1b, rowptr, esrc, Hbuf);
    k_mlp<1, 0><<<GB, 256, 0, stream>>>(Hbuf,
                                        wth + 2 * HD * HD, wtl + 2 * HD * HD, b1a,
                                        wth + 3 * HD * HD, wtl + 3 * HD * HD, b1b,
                                        outP, nullptr, ps1);

    // ---- z stats reduce + BN finalize; proj (BN-apply + z-write + partial p-stats) ----
    k_sred<<<64, 256, 0, stream>>>(ps1, GB, pb2a);
    k_bnfin<<<1, 128, 0, stream>>>(pb2a, bng, bnb, st + 256, st + 384);
    k_proj<<<GB, 256, 0, stream>>>(outP, st + 256, st + 384, outZ,
                                   wth + 4 * HD * HD, wtl + 4 * HD * HD, pb,
                                   outP, ps2);

    // ---- p stats reduce -> BN -> PReLU (in place) ----
    k_sred<<<64, 256, 0, stream>>>(ps2, GB, pb2b);
    k_bnfin<<<1, 128, 0, stream>>>(pb2b, pbng, pbnb, st + 768, st + 896);
    k_bnapply<<<ELV, 256, 0, stream>>>(outP, st + 768, st + 896, outP, pa);
}

// Round 12
// 310.062 us; speedup vs baseline: 1.0624x; 1.0624x over previous
//
#include <hip/hip_runtime.h>
#include <hip/hip_bf16.h>

#define NN 50000
#define NE 800000
#define HD 128
#define BN_EPS 1e-5f
#define MSTR 132     // padded LDS stride (floats)
#define NBUK 782     // ceil(NN/64) coarse buckets
#define PB 200       // partition blocks for bucket count/scatter
#define CHUNK 4000   // NE / PB

typedef __attribute__((ext_vector_type(8))) __bf16 bf16x8;
typedef __attribute__((ext_vector_type(4))) __bf16 bf16x4;
typedef __attribute__((ext_vector_type(4))) float floatx4;

// ---------------- merged prep: W split/pack + x cast + bucket count ----------------
// blocks [0,320): wprep; [320,3445): cast; [3445,3645): bcount.
// gbtot zeroed via hipMemsetAsync before this kernel (cross-block ordering!).
__global__ __launch_bounds__(256) void k_prep(const float* __restrict__ W0,
                                              const float* __restrict__ W1,
                                              const float* __restrict__ W2,
                                              const float* __restrict__ W3,
                                              const float* __restrict__ W4,
                                              __bf16* __restrict__ Bh,
                                              __bf16* __restrict__ Bl,
                                              const float* __restrict__ X,
                                              __bf16* __restrict__ Y,
                                              const int* __restrict__ dst,
                                              int* __restrict__ gbtot) {
    __shared__ int h[NBUK];
    const int b = blockIdx.x;
    if (b < 320) {
        // ---- W prep: split bf16 hi/lo, packed in wave-load order ----
        const int t = b * 256 + threadIdx.x;          // 81920 = 5*128*128
        const int m = t >> 14;
        const int rem = t & 16383;
        const int n = rem >> 7;
        const int k = rem & 127;
        const float* W = (m == 0) ? W0 : (m == 1) ? W1 : (m == 2) ? W2 : (m == 3) ? W3 : W4;
        const float w = W[k * HD + n];
        const __bf16 hi = (__bf16)w;
        const int ct = n >> 4, lm = n & 15;
        const int ks = k >> 5, lq = (k & 31) >> 3, j = k & 7;
        const int lane = lq * 16 + lm;
        const size_t o = (size_t)m * HD * HD + (size_t)(((ct * 4 + ks) * 64) + lane) * 8 + j;
        Bh[o] = hi;
        Bl[o] = (__bf16)(w - (float)hi);
    } else if (b < 320 + 3125) {
        // ---- f32 -> bf16 cast, 8 elems/lane ----
        const int i8 = ((b - 320) * 256 + threadIdx.x) * 8;
        const float4 a = *(const float4*)&X[i8];
        const float4 c = *(const float4*)&X[i8 + 4];
        bf16x8 o;
        o[0] = (__bf16)a.x; o[1] = (__bf16)a.y; o[2] = (__bf16)a.z; o[3] = (__bf16)a.w;
        o[4] = (__bf16)c.x; o[5] = (__bf16)c.y; o[6] = (__bf16)c.z; o[7] = (__bf16)c.w;
        *(bf16x8*)&Y[i8] = o;
    } else {
        // ---- bucket count (LDS histogram) ----
        for (int i = threadIdx.x; i < NBUK; i += 256) h[i] = 0;
        __syncthreads();
        const int e0 = (b - (320 + 3125)) * CHUNK;
        for (int i = threadIdx.x; i < CHUNK; i += 256)
            atomicAdd(&h[dst[e0 + i] >> 6], 1);
        __syncthreads();
        for (int i = threadIdx.x; i < NBUK; i += 256) {
            const int v = h[i];
            if (v) atomicAdd(&gbtot[i], v);
        }
    }
}

// ---------------- CSR build: scan / scatter / finalize ----------------
__global__ __launch_bounds__(256) void k_bscan(const int* __restrict__ gbtot,
                                               int* __restrict__ bbase,
                                               int* __restrict__ gcur,
                                               int* __restrict__ rowptr) {
    __shared__ int sh[256];
    const int t = threadIdx.x;
    int v[4];
    int s = 0;
#pragma unroll
    for (int j = 0; j < 4; ++j) {
        const int idx = t * 4 + j;
        v[j] = (idx < NBUK) ? gbtot[idx] : 0;
        s += v[j];
    }
    sh[t] = s;
    __syncthreads();
#pragma unroll
    for (int st = 1; st < 256; st <<= 1) {
        int add = (t >= st) ? sh[t - st] : 0;
        __syncthreads();
        sh[t] += add;
        __syncthreads();
    }
    int run = sh[t] - s;  // exclusive
#pragma unroll
    for (int j = 0; j < 4; ++j) {
        const int idx = t * 4 + j;
        if (idx < NBUK) { bbase[idx] = run; gcur[idx] = run; }
        run += v[j];
    }
    if (t == 255) bbase[NBUK] = run;   // == NE
    if (t == 0) rowptr[NN] = NE;
}

// pairs packed: (dst & 63) << 17 | src  (src < 50000 < 2^17) — 4 B/edge, halves
// scatter write + finalize read traffic vs int2.
__global__ __launch_bounds__(256) void k_bscatter(const int* __restrict__ src,
                                                  const int* __restrict__ dst,
                                                  int* __restrict__ gcur,
                                                  unsigned* __restrict__ pairs) {
    __shared__ int h[NBUK];
    __shared__ int cur[NBUK];
    for (int i = threadIdx.x; i < NBUK; i += 256) h[i] = 0;
    __syncthreads();
    const int e0 = blockIdx.x * CHUNK;
    for (int i = threadIdx.x; i < CHUNK; i += 256)
        atomicAdd(&h[dst[e0 + i] >> 6], 1);
    __syncthreads();
    for (int i = threadIdx.x; i < NBUK; i += 256) {
        const int v = h[i];
        if (v) cur[i] = atomicAdd(&gcur[i], v);   // block-reserve per bucket
    }
    __syncthreads();
    for (int i = threadIdx.x; i < CHUNK; i += 256) {
        const int d = dst[e0 + i];
        const int pos = atomicAdd(&cur[d >> 6], 1);
        pairs[pos] = ((unsigned)(d & 63) << 17) | (unsigned)src[e0 + i];
    }
}

__global__ __launch_bounds__(256) void k_csrfin(const unsigned* __restrict__ pairs,
                                                const int* __restrict__ bbase,
                                                int* __restrict__ rowptr,
                                                int* __restrict__ esrc) {
    __shared__ int cnt[64], lof[64], cur[64];
    const int b = blockIdx.x;
    const int s = bbase[b], e = bbase[b + 1];
    const int tid = threadIdx.x;
    if (tid < 64) cnt[tid] = 0;
    __syncthreads();
    for (int i = s + tid; i < e; i += 256)
        atomicAdd(&cnt[pairs[i] >> 17], 1);
    __syncthreads();
    if (tid == 0) {
        int r = 0;
#pragma unroll
        for (int j = 0; j < 64; ++j) { lof[j] = r; cur[j] = r; r += cnt[j]; }
    }
    __syncthreads();
    if (tid < 64) {
        const int node = b * 64 + tid;
        if (node < NN) rowptr[node] = s + lof[tid];
    }
    for (int i = s + tid; i < e; i += 256) {
        const unsigned p = pairs[i];
        const int pos = atomicAdd(&cur[p >> 17], 1);
        esrc[s + pos] = (int)(p & 0x1FFFFu);
    }
}

// ---------------- helper: split float8 into bf16 hi/lo fragments ----------------
__device__ __forceinline__ void split8(const float4 a, const float4 b,
                                       bf16x8& hi, bf16x8& lo) {
    hi[0] = (__bf16)a.x; lo[0] = (__bf16)(a.x - (float)hi[0]);
    hi[1] = (__bf16)a.y; lo[1] = (__bf16)(a.y - (float)hi[1]);
    hi[2] = (__bf16)a.z; lo[2] = (__bf16)(a.z - (float)hi[2]);
    hi[3] = (__bf16)a.w; lo[3] = (__bf16)(a.w - (float)hi[3]);
    hi[4] = (__bf16)b.x; lo[4] = (__bf16)(b.x - (float)hi[4]);
    hi[5] = (__bf16)b.y; lo[5] = (__bf16)(b.y - (float)hi[5]);
    hi[6] = (__bf16)b.z; lo[6] = (__bf16)(b.z - (float)hi[6]);
    hi[7] = (__bf16)b.w; lo[7] = (__bf16)(b.w - (float)hi[7]);
}

// ---------------- helper: unpack-accumulate 8 bf16 into two float4 ----------------
__device__ __forceinline__ void addb8(float4& a, float4& b, const bf16x8 v) {
    a.x += (float)v[0]; a.y += (float)v[1]; a.z += (float)v[2]; a.w += (float)v[3];
    b.x += (float)v[4]; b.y += (float)v[5]; b.z += (float)v[6]; b.w += (float)v[7];
}

// ---------------- gather-aggregate (bf16 rows): H[i] = Z[i] + sum_{j->i} Z[j] ----------------
// r10 shape (16 lanes/node, 256 thr) + 16-deep unroll tier: avg degree 16 ->
// most nodes complete in ONE batch of 16 outstanding 16B loads (latency MLP).
__global__ __launch_bounds__(256) void k_aggb(const __bf16* __restrict__ Z,
                                              const int* __restrict__ rowptr,
                                              const int* __restrict__ esrc,
                                              float* __restrict__ H) {
    const int g = threadIdx.x >> 4;
    const int lg = threadIdx.x & 15;
    const int node = blockIdx.x * 16 + g;
    const int cb = lg * 8;
    const int start = rowptr[node], end = rowptr[node + 1];
    float4 a = {0.f, 0.f, 0.f, 0.f}, b = {0.f, 0.f, 0.f, 0.f};
    addb8(a, b, *(const bf16x8*)&Z[(size_t)node * HD + cb]);
    int k = start;
    for (; k + 16 <= end; k += 16) {   // 16 outstanding 16B loads / lane
        int s[16];
#pragma unroll
        for (int j = 0; j < 16; ++j) s[j] = esrc[k + j];
        bf16x8 v[16];
#pragma unroll
        for (int j = 0; j < 16; ++j) v[j] = *(const bf16x8*)&Z[(size_t)s[j] * HD + cb];
#pragma unroll
        for (int j = 0; j < 16; ++j) addb8(a, b, v[j]);
    }
    for (; k + 4 <= end; k += 4) {
        const int s0 = esrc[k + 0], s1 = esrc[k + 1];
        const int s2 = esrc[k + 2], s3 = esrc[k + 3];
        const bf16x8 v0 = *(const bf16x8*)&Z[(size_t)s0 * HD + cb];
        const bf16x8 v1 = *(const bf16x8*)&Z[(size_t)s1 * HD + cb];
        const bf16x8 v2 = *(const bf16x8*)&Z[(size_t)s2 * HD + cb];
        const bf16x8 v3 = *(const bf16x8*)&Z[(size_t)s3 * HD + cb];
        addb8(a, b, v0); addb8(a, b, v1); addb8(a, b, v2); addb8(a, b, v3);
    }
    for (; k < end; ++k) {
        const int s = esrc[k];
        addb8(a, b, *(const bf16x8*)&Z[(size_t)s * HD + cb]);
    }
    *(float4*)&H[(size_t)node * HD + cb] = a;
    *(float4*)&H[(size_t)node * HD + cb + 4] = b;
}

// ---------------- B staging (global -> regs -> LDS), 16 chunks of 1KB per ks-panel ----------------
// wave wid stages chunks [wid*4, wid*4+4): chunks 0-7 = hi ct0-7, 8-15 = lo ct0-7.
struct StageRegs { bf16x8 v[4]; };

__device__ __forceinline__ void stage_load(StageRegs& s, const __bf16* __restrict__ Bh,
                                           const __bf16* __restrict__ Bl,
                                           int ks, int wid, int lane) {
#pragma unroll
    for (int i = 0; i < 4; ++i) {
        const int chunk = wid * 4 + i;
        const int ct = chunk & 7;
        const __bf16* base = (chunk < 8) ? Bh : Bl;
        s.v[i] = *(const bf16x8*)&base[(size_t)(((ct * 4 + ks) * 64) + lane) * 8];
    }
}
__device__ __forceinline__ void stage_write(const StageRegs& s, __bf16* Bb,
                                            int wid, int lane) {
#pragma unroll
    for (int i = 0; i < 4; ++i) {
        const int chunk = wid * 4 + i;
        *(bf16x8*)&Bb[chunk * 512 + lane * 8] = s.v[i];
    }
}

// ---------------- helper: bf16x3 K-pass reading B panel from LDS (batched) ----------------
__device__ __forceinline__ void mfma_pass_lds(floatx4 (&acc)[8], const bf16x8 ah,
                                              const bf16x8 al, const __bf16* Bb,
                                              int lane) {
    bf16x8 bh[8], bl[8];
#pragma unroll
    for (int ct = 0; ct < 8; ++ct) {
        bh[ct] = *(const bf16x8*)&Bb[ct * 512 + lane * 8];
        bl[ct] = *(const bf16x8*)&Bb[(8 + ct) * 512 + lane * 8];
    }
    __builtin_amdgcn_sched_barrier(0);
#pragma unroll
    for (int ct = 0; ct < 8; ++ct) {
        acc[ct] = __builtin_amdgcn_mfma_f32_16x16x32_bf16(al, bh[ct], acc[ct], 0, 0, 0);
        acc[ct] = __builtin_amdgcn_mfma_f32_16x16x32_bf16(ah, bl[ct], acc[ct], 0, 0, 0);
        acc[ct] = __builtin_amdgcn_mfma_f32_16x16x32_bf16(ah, bh[ct], acc[ct], 0, 0, 0);
    }
}

// ---------------- fused GIN MLP: C = relu(relu(A@W1+b1)@W2+b2) ----------------
// B panels LDS-staged once per block, shared by all 4 waves. 8 phases (4 ks x 2
// GEMMs), double-buffered, T14 pattern: issue loads -> compute -> write -> barrier.
template <int STATS, int OUT16>
__global__ __launch_bounds__(256) void k_mlp(const float* __restrict__ A,
                                             const __bf16* __restrict__ Bh1,
                                             const __bf16* __restrict__ Bl1,
                                             const float* __restrict__ b1,
                                             const __bf16* __restrict__ Bh2,
                                             const __bf16* __restrict__ Bl2,
                                             const float* __restrict__ b2,
                                             float* __restrict__ C,
                                             __bf16* __restrict__ C16,
                                             float* __restrict__ pstat) {
    __shared__ float mid[4][16 * MSTR];   // 33792 B, per-wave scratch
    __shared__ __bf16 Bb[2][16 * 512];    // 32768 B, double-buffered B panel
    __shared__ float ssum[128], ssq[128];
    const int tid = threadIdx.x;
    const int wid = tid >> 6, lane = tid & 63;
    const int lq = lane >> 4, lm = lane & 15;
    if (STATS && tid < 128) { ssum[tid] = 0.f; ssq[tid] = 0.f; }
    const int rowbase = blockIdx.x * 64 + wid * 16;
    const int r0 = min(rowbase + lm, NN - 1);
    float* m = &mid[wid][0];

    // ---- A preload for GEMM1 (all 4 ks) ----
    bf16x8 ahv[4], alv[4];
    {
        float4 av[8];
#pragma unroll
        for (int ks = 0; ks < 4; ++ks) {
            const int kk = ks * 32 + lq * 8;
            av[ks * 2 + 0] = *(const float4*)&A[(size_t)r0 * HD + kk];
            av[ks * 2 + 1] = *(const float4*)&A[(size_t)r0 * HD + kk + 4];
        }
#pragma unroll
        for (int ks = 0; ks < 4; ++ks)
            split8(av[ks * 2], av[ks * 2 + 1], ahv[ks], alv[ks]);
    }
    // ---- prologue: stage phase-0 panel ----
    {
        StageRegs s;
        stage_load(s, Bh1, Bl1, 0, wid, lane);
        stage_write(s, &Bb[0][0], wid, lane);
    }
    __syncthreads();

    floatx4 acc[8];
#pragma unroll
    for (int j = 0; j < 8; ++j) acc[j] = (floatx4){0.f, 0.f, 0.f, 0.f};

#pragma unroll
    for (int p = 0; p < 8; ++p) {
        // 1. issue next-panel loads (hidden under compute)
        StageRegs s;
        if (p < 7) {
            const int pn = p + 1;
            stage_load(s, (pn < 4) ? Bh1 : Bh2, (pn < 4) ? Bl1 : Bl2, pn & 3, wid, lane);
        }
        // 2. compute this phase
        bf16x8 ah, al;
        if (p < 4) { ah = ahv[p]; al = alv[p]; }
        else {
            const int kk = (p & 3) * 32 + lq * 8;
            const float4 aa = *(const float4*)&m[lm * MSTR + kk];
            const float4 ab = *(const float4*)&m[lm * MSTR + kk + 4];
            split8(aa, ab, ah, al);
        }
        mfma_pass_lds(acc, ah, al, &Bb[p & 1][0], lane);
        // 3. GEMM1 epilogue between phases 3 and 4 (per-wave mid, no barrier needed)
        if (p == 3) {
#pragma unroll
            for (int ct = 0; ct < 8; ++ct) {
                const int col = ct * 16 + lm;
                const float bcol = b1[col];
#pragma unroll
                for (int r = 0; r < 4; ++r)
                    m[(lq * 4 + r) * MSTR + col] = fmaxf(acc[ct][r] + bcol, 0.f);
            }
#pragma unroll
            for (int j = 0; j < 8; ++j) acc[j] = (floatx4){0.f, 0.f, 0.f, 0.f};
        }
        // 4. land the staged panel, fence all waves
        if (p < 7) stage_write(s, &Bb[(p + 1) & 1][0], wid, lane);
        __syncthreads();
    }
    // ---- epilogue: transpose via LDS -> coalesced stores (+stats) ----
#pragma unroll
    for (int ct = 0; ct < 8; ++ct) {
        const int col = ct * 16 + lm;
        const float bcol = b2[col];
#pragma unroll
        for (int r = 0; r < 4; ++r)
            m[(lq * 4 + r) * MSTR + col] = fmaxf(acc[ct][r] + bcol, 0.f);
    }
    float s0 = 0.f, s1 = 0.f, s2 = 0.f, s3 = 0.f;
    float q0 = 0.f, q1 = 0.f, q2 = 0.f, q3 = 0.f;
    const int c0 = (lane * 4) & 127;
#pragma unroll
    for (int p = 0; p < 8; ++p) {
        const int idx = p * 256 + lane * 4;
        const int r = idx >> 7;
        const float4 v = *(const float4*)&m[r * MSTR + c0];
        const int row = rowbase + r;
        if (row < NN) {
            if (OUT16) {
                bf16x4 o;
                o[0] = (__bf16)v.x; o[1] = (__bf16)v.y;
                o[2] = (__bf16)v.z; o[3] = (__bf16)v.w;
                *(bf16x4*)&C16[(size_t)row * HD + c0] = o;
            } else {
                *(float4*)&C[(size_t)row * HD + c0] = v;
            }
            if (STATS) {
                s0 += v.x; q0 = fmaf(v.x, v.x, q0);
                s1 += v.y; q1 = fmaf(v.y, v.y, q1);
                s2 += v.z; q2 = fmaf(v.z, v.z, q2);
                s3 += v.w; q3 = fmaf(v.w, v.w, q3);
            }
        }
    }
    if (STATS) {
        s0 += __shfl_xor(s0, 32); q0 += __shfl_xor(q0, 32);
        s1 += __shfl_xor(s1, 32); q1 += __shfl_xor(q1, 32);
        s2 += __shfl_xor(s2, 32); q2 += __shfl_xor(q2, 32);
        s3 += __shfl_xor(s3, 32); q3 += __shfl_xor(q3, 32);
        if (lane < 32) {
            atomicAdd(&ssum[c0 + 0], s0); atomicAdd(&ssq[c0 + 0], q0);
            atomicAdd(&ssum[c0 + 1], s1); atomicAdd(&ssq[c0 + 1], q1);
            atomicAdd(&ssum[c0 + 2], s2); atomicAdd(&ssq[c0 + 2], q2);
            atomicAdd(&ssum[c0 + 3], s3); atomicAdd(&ssq[c0 + 3], q3);
        }
        __syncthreads();
        if (tid < 128) {   // contention-free partial store
            pstat[(size_t)blockIdx.x * 256 + tid] = ssum[tid];
            pstat[(size_t)blockIdx.x * 256 + 128 + tid] = ssq[tid];
        }
    }
}

// ---------------- projection GEMM: LDS-staged B, FUSED z-BN-finalize prologue ----------------
// Each block derives z scale/shift from pb2a (64x256 partials, L2-hot) into LDS —
// removes the 1-block k_bnfin launch + its full-drain serialization.
__global__ __launch_bounds__(256) void k_proj(const float* __restrict__ Z2,
                                              const float* __restrict__ pb2a,
                                              const float* __restrict__ gamma,
                                              const float* __restrict__ beta,
                                              float* __restrict__ Zout,
                                              const __bf16* __restrict__ Bh,
                                              const __bf16* __restrict__ Bl,
                                              const float* __restrict__ bias,
                                              float* __restrict__ C,
                                              float* __restrict__ pstat) {
    __shared__ union {                    // B panel (phases) then epilogue tile
        __bf16 bb[2][16 * 512];           // 32768 B
        float tb[4][16 * MSTR];           // 33792 B
    } u;
    __shared__ float ssum[128], ssq[128];
    __shared__ float scs[128], shs[128];
    const int tid = threadIdx.x;
    const int wid = tid >> 6, lane = tid & 63;
    const int lq = lane >> 4, lm = lane & 15;
    if (tid < 128) {
        ssum[tid] = 0.f; ssq[tid] = 0.f;
        float s = 0.f, q = 0.f;
        for (int b = 0; b < 64; ++b) {
            s += pb2a[b * 256 + tid];
            q += pb2a[b * 256 + 128 + tid];
        }
        const float mean = s * (1.f / NN);
        const float var = q * (1.f / NN) - mean * mean;
        const float sc = gamma[tid] * rsqrtf(var + BN_EPS);
        scs[tid] = sc;
        shs[tid] = beta[tid] - mean * sc;
    }
    __syncthreads();
    const int rowbase = blockIdx.x * 64 + wid * 16;
    const int r0 = min(rowbase + lm, NN - 1);
    const bool rowok = (rowbase + lm) < NN;
    float* m = &u.tb[wid][0];

    // ---- preload A' = BN(z2) for all ks; write Zout ----
    bf16x8 ahv[4], alv[4];
#pragma unroll
    for (int ks = 0; ks < 4; ++ks) {
        const int kk = ks * 32 + lq * 8;
        const float4 za = *(const float4*)&Z2[(size_t)r0 * HD + kk];
        const float4 zb = *(const float4*)&Z2[(size_t)r0 * HD + kk + 4];
        const float4 sca = *(const float4*)&scs[kk];
        const float4 scb = *(const float4*)&scs[kk + 4];
        const float4 sha = *(const float4*)&shs[kk];
        const float4 shb = *(const float4*)&shs[kk + 4];
        float4 aa, ab;
        aa.x = fmaf(za.x, sca.x, sha.x); aa.y = fmaf(za.y, sca.y, sha.y);
        aa.z = fmaf(za.z, sca.z, sha.z); aa.w = fmaf(za.w, sca.w, sha.w);
        ab.x = fmaf(zb.x, scb.x, shb.x); ab.y = fmaf(zb.y, scb.y, shb.y);
        ab.z = fmaf(zb.z, scb.z, shb.z); ab.w = fmaf(zb.w, scb.w, shb.w);
        if (rowok) {
            *(float4*)&Zout[(size_t)r0 * HD + kk] = aa;
            *(float4*)&Zout[(size_t)r0 * HD + kk + 4] = ab;
        }
        split8(aa, ab, ahv[ks], alv[ks]);
    }
    // ---- prologue: stage ks=0 panel ----
    {
        StageRegs s;
        stage_load(s, Bh, Bl, 0, wid, lane);
        stage_write(s, &u.bb[0][0], wid, lane);
    }
    __syncthreads();

    floatx4 acc[8];
#pragma unroll
    for (int j = 0; j < 8; ++j) acc[j] = (floatx4){0.f, 0.f, 0.f, 0.f};
#pragma unroll
    for (int p = 0; p < 4; ++p) {
        StageRegs s;
        if (p < 3) stage_load(s, Bh, Bl, p + 1, wid, lane);
        mfma_pass_lds(acc, ahv[p], alv[p], &u.bb[p & 1][0], lane);
        if (p < 3) stage_write(s, &u.bb[(p + 1) & 1][0], wid, lane);
        __syncthreads();
    }
    // ---- epilogue: transpose (tb overlays bb; barrier above fences last reads) ----
#pragma unroll
    for (int ct = 0; ct < 8; ++ct) {
        const int col = ct * 16 + lm;
        const float bcol = bias[col];
#pragma unroll
        for (int r = 0; r < 4; ++r)
            m[(lq * 4 + r) * MSTR + col] = acc[ct][r] + bcol;
    }
    float s0 = 0.f, s1 = 0.f, s2 = 0.f, s3 = 0.f;
    float q0 = 0.f, q1 = 0.f, q2 = 0.f, q3 = 0.f;
    const int c0 = (lane * 4) & 127;
#pragma unroll
    for (int p = 0; p < 8; ++p) {
        const int idx = p * 256 + lane * 4;
        const int r = idx >> 7;
        const float4 v = *(const float4*)&m[r * MSTR + c0];
        const int row = rowbase + r;
        if (row < NN) {
            *(float4*)&C[(size_t)row * HD + c0] = v;
            s0 += v.x; q0 = fmaf(v.x, v.x, q0);
            s1 += v.y; q1 = fmaf(v.y, v.y, q1);
            s2 += v.z; q2 = fmaf(v.z, v.z, q2);
            s3 += v.w; q3 = fmaf(v.w, v.w, q3);
        }
    }
    s0 += __shfl_xor(s0, 32); q0 += __shfl_xor(q0, 32);
    s1 += __shfl_xor(s1, 32); q1 += __shfl_xor(q1, 32);
    s2 += __shfl_xor(s2, 32); q2 += __shfl_xor(q2, 32);
    s3 += __shfl_xor(s3, 32); q3 += __shfl_xor(q3, 32);
    if (lane < 32) {
        atomicAdd(&ssum[c0 + 0], s0); atomicAdd(&ssq[c0 + 0], q0);
        atomicAdd(&ssum[c0 + 1], s1); atomicAdd(&ssq[c0 + 1], q1);
        atomicAdd(&ssum[c0 + 2], s2); atomicAdd(&ssq[c0 + 2], q2);
        atomicAdd(&ssum[c0 + 3], s3); atomicAdd(&ssq[c0 + 3], q3);
    }
    __syncthreads();
    if (tid < 128) {   // contention-free partial store
        pstat[(size_t)blockIdx.x * 256 + tid] = ssum[tid];
        pstat[(size_t)blockIdx.x * 256 + 128 + tid] = ssq[tid];
    }
}

// ---------------- stats reduce: NBLK x 256 partials -> 64 x 256 ----------------
__global__ __launch_bounds__(256) void k_sred(const float* __restrict__ ps, int nblk,
                                              float* __restrict__ out) {
    const int j = threadIdx.x;
    float acc = 0.f;
    for (int r = blockIdx.x; r < nblk; r += 64)
        acc += ps[(size_t)r * 256 + j];
    out[blockIdx.x * 256 + j] = acc;
}

// ---------------- BN finalize (sums 64 partial rows) ----------------
__global__ void k_bnfin(const float* __restrict__ pb2,
                        const float* __restrict__ gamma, const float* __restrict__ beta,
                        float* __restrict__ scale, float* __restrict__ shift) {
    const int c = threadIdx.x;
    float s = 0.f, q = 0.f;
    for (int b = 0; b < 64; ++b) {
        s += pb2[b * 256 + c];
        q += pb2[b * 256 + 128 + c];
    }
    const float mean = s * (1.f / NN);
    const float var = q * (1.f / NN) - mean * mean;
    const float sc = gamma[c] * rsqrtf(var + BN_EPS);
    scale[c] = sc;
    shift[c] = beta[c] - mean * sc;
}

// ---------------- BN apply + PReLU, float4, in-place ----------------
__global__ void k_bnapply(const float* __restrict__ X, const float* __restrict__ scale,
                          const float* __restrict__ shift, float* __restrict__ Y,
                          const float* __restrict__ pa) {
    const int i4 = (blockIdx.x * 256 + threadIdx.x) * 4;
    const int c = i4 & 127;
    const float4 sc = *(const float4*)&scale[c];
    const float4 sh = *(const float4*)&shift[c];
    const float4 v = *(const float4*)&X[i4];
    float4 y;
    y.x = fmaf(v.x, sc.x, sh.x);
    y.y = fmaf(v.y, sc.y, sh.y);
    y.z = fmaf(v.z, sc.z, sh.z);
    y.w = fmaf(v.w, sc.w, sh.w);
    const float a = pa[0];
    if (y.x < 0.f) y.x *= a;
    if (y.y < 0.f) y.y *= a;
    if (y.z < 0.f) y.z *= a;
    if (y.w < 0.f) y.w *= a;
    *(float4*)&Y[i4] = y;
}

extern "C" void kernel_launch(void* const* d_in, const int* in_sizes, int n_in,
                              void* d_out, int out_size, void* d_ws, size_t ws_size,
                              hipStream_t stream) {
    const float* x = (const float*)d_in[0];
    const int* ei = (const int*)d_in[1];
    const float* w0a = (const float*)d_in[2];
    const float* b0a = (const float*)d_in[3];
    const float* w0b = (const float*)d_in[4];
    const float* b0b = (const float*)d_in[5];
    const float* w1a = (const float*)d_in[6];
    const float* b1a = (const float*)d_in[7];
    const float* w1b = (const float*)d_in[8];
    const float* b1b = (const float*)d_in[9];
    const float* bng = (const float*)d_in[10];
    const float* bnb = (const float*)d_in[11];
    const float* pw  = (const float*)d_in[12];
    const float* pb  = (const float*)d_in[13];
    const float* pbng = (const float*)d_in[14];
    const float* pbnb = (const float*)d_in[15];
    const float* pa = (const float*)d_in[16];

    float* outZ = (float*)d_out;                    // (NN,128) f32 — z
    float* outP = outZ + (size_t)NN * HD;           // (NN,128) f32 — H scratch / z2 / p

    float* ws = (float*)d_ws;
    float* bufH = ws;                               // 25.6 MB: xb (bf16) + z1b/pairs
    float* st = bufH + (size_t)NN * HD;             // 1024 floats (scale/shift slots)
    int* rowptr = (int*)(st + 1024);                // NN+1 (+pad)
    int* esrc = rowptr + NN + 64;                   // NE
    int* gbtot = esrc + NE;                         // 782 (pad 800)
    int* bbase = gbtot + 800;                       // 783 (pad 800)
    int* gcur = bbase + 800;                        // 782 (pad 800)
    __bf16* wth = (__bf16*)(gcur + 800);            // 5*128*128 bf16 hi (packed)
    __bf16* wtl = wth + 5 * HD * HD;                // 5*128*128 bf16 lo (packed)
    float* ps1 = (float*)(wtl + 5 * HD * HD);       // 782*256 f32 — z-stat partials
    float* pb2a = ps1 + 800 * 256;                  // 64*256
    float* ps2 = pb2a + 64 * 256;                   // 782*256 — p-stat partials
    float* pb2b = ps2 + 800 * 256;                  // 64*256

    __bf16* xb  = (__bf16*)bufH;                    // (NN,128) bf16 — cast of x
    __bf16* z1b = xb + (size_t)NN * HD;             // (NN,128) bf16 — z1
    unsigned* pairs = (unsigned*)z1b;               // 3.2 MB — packed CSR scratch (aliases
                                                    //   z1b; consumed before z1b write)
    float* Hbuf = outP;                             // aggregate scratch (aliases outP)

    const int* srcv = ei;
    const int* dstv = ei + NE;

    const int ELV = (NN * HD) / (256 * 4);
    const int GB = (NN + 63) / 64;                  // 782
    const int AB = NN / 16;                         // 3125
    const int PREPB = 320 + 3125 + PB;              // 3645

    // ---- zero bucket totals, then merged prep (wprep ∥ cast ∥ bcount) ----
    hipMemsetAsync(gbtot, 0, 800 * sizeof(int), stream);
    k_prep<<<PREPB, 256, 0, stream>>>(w0a, w0b, w1a, w1b, pw, wth, wtl,
                                      x, xb, dstv, gbtot);

    // ---- CSR build: scan -> scatter packed pairs -> finalize ----
    k_bscan<<<1, 256, 0, stream>>>(gbtot, bbase, gcur, rowptr);
    k_bscatter<<<PB, 256, 0, stream>>>(srcv, dstv, gcur, pairs);
    k_csrfin<<<NBUK, 256, 0, stream>>>(pairs, bbase, rowptr, esrc);

    // ---- GIN layer 0: H = x + agg(x) (bf16 gather); z1b = relu(MLP0(H)) ----
    k_aggb<<<AB, 256, 0, stream>>>(xb, rowptr, esrc, Hbuf);
    k_mlp<0, 1><<<GB, 256, 0, stream>>>(Hbuf,
                                        wth + 0 * HD * HD, wtl + 0 * HD * HD, b0a,
                                        wth + 1 * HD * HD, wtl + 1 * HD * HD, b0b,
                                        nullptr, z1b, nullptr);

    // ---- GIN layer 1: H = z1 + agg(z1); z2 = relu(MLP1(H)) -> outP, partial z-stats ----
    k_aggb<<<AB, 256, 0, stream>>>(z1b, rowptr, esrc, Hbuf);
    k_mlp<1, 0><<<GB, 256, 0, stream>>>(Hbuf,
                                        wth + 2 * HD * HD, wtl + 2 * HD * HD, b1a,
                                        wth + 3 * HD * HD, wtl + 3 * HD * HD, b1b,
                                        outP, nullptr, ps1);

    // ---- z stats reduce; proj fuses z-BN-finalize + BN-apply + z-write + p-stats ----
    k_sred<<<64, 256, 0, stream>>>(ps1, GB, pb2a);
    k_proj<<<GB, 256, 0, stream>>>(outP, pb2a, bng, bnb, outZ,
                                   wth + 4 * HD * HD, wtl + 4 * HD * HD, pb,
                                   outP, ps2);

    // ---- p stats reduce -> BN -> PReLU (in place) ----
    k_sred<<<64, 256, 0, stream>>>(ps2, GB, pb2b);
    k_bnfin<<<1, 128, 0, stream>>>(pb2b, pbng, pbnb, st + 768, st + 896);
    k_bnapply<<<ELV, 256, 0, stream>>>(outP, st + 768, st + 896, outP, pa);
}